// Round 4
// baseline (248.912 us; speedup 1.0000x reference)
//
#include <hip/hip_runtime.h>
#include <hip/hip_cooperative_groups.h>
#include <math.h>

// SDFNet: conv1x1(1->8) -> 16x (h += minpool3(h)) -> conv3x3(8->32) -> relu -> conv1x1(32->1)
//
// Factorization: erosion steps act per-channel on affine maps of x.
//   w0[c] > 0: h_c after 16 iters = w0[c]*P16(x) + b0[c]*2^16   (P = min-iterate of x)
//   w0[c] < 0: h_c = |w0[c]|*Q16 + b0[c]*2^16, Q = min-iterate of -x (pad +inf exact)
// Head = 3x3 conv over (P,Q) with folded weights, bias beta = 65536*sum_ic b0*w1
// applied only for in-image taps (ref zero-pads h).
//
// R8:  cross-lane +/-1 shifts via wave-wide DPP (old = INF/0 fill).
// R9:  2 erosion steps per barrier; prep folded into erode.
// R13: row_update8 via v_min3_f32 (26 VALU); bands 0/7 whole-body cone skip s>=4.
// R14: b128 halo exchange (XOR-16B swizzle, 2-way banks); head packs oc-pairs in
//      f2 with P/Q broadcast via VOP3P op_sel pk_fma.  [both kept: neutral-to-+]
// R15: SINGLE COOPERATIVE KERNEL: erode -> threadfence + grid.sync -> head.
//      Removes the 2nd dispatch (launch gap + full-grid drain + head cold start).
//      256 blocks x 512 thr, 128 KB LDS = 1 block/CU -> all co-resident.
//      Head re-gridded: block (ty,plane) does 16 rows of img=plane&7 (P-blocks
//      lower half-tile, Q-blocks upper) so half the A-reads are same-XCD L2 hits.
//      grid.sync() provides device-scope release/acquire for the cross-XCD A/W
//      handoff (replaces the implicit inter-kernel flush; G16).

#define N_PIX (512*512)
#define INF __builtin_inff()

namespace cg = cooperative_groups;

typedef __attribute__((ext_vector_type(2))) float f2;

__device__ __forceinline__ unsigned long long f2bits(f2 v) {
    union { f2 f; unsigned long long u; } c; c.f = v; return c.u;
}
__device__ __forceinline__ f2 bits2f(unsigned long long u) {
    union { f2 f; unsigned long long u; } c; c.u = u; return c.f;
}

// lane l gets v[l-1]; lane 0 gets `fill`   (DPP wave_shr1 = 0x138, VALU pipe)
__device__ __forceinline__ float dpp_shr1(float v, float fill) {
    return __int_as_float(__builtin_amdgcn_update_dpp(
        __float_as_int(fill), __float_as_int(v), 0x138, 0xF, 0xF, false));
}
// lane l gets v[l+1]; lane 63 gets `fill`  (DPP wave_shl1 = 0x130)
__device__ __forceinline__ float dpp_shl1(float v, float fill) {
    return __int_as_float(__builtin_amdgcn_update_dpp(
        __float_as_int(fill), __float_as_int(v), 0x130, 0xF, 0xF, false));
}
// single-instruction 3-input min (IEEE minnum semantics, exact for finite/+inf)
__device__ __forceinline__ float vmin3(float a, float b, float c) {
    float d;
    asm("v_min3_f32 %0, %1, %2, %3" : "=v"(d) : "v"(a), "v"(b), "v"(c));
    return d;
}

// ---- packed fma with scalar broadcast via op_sel --------------------------
// acc.{lo,hi} += w.{lo,hi} * pq.lo   (P broadcast: src1 lo word for both halves)
__device__ __forceinline__ void pkfma_P(f2& acc, unsigned long long w, f2 pq) {
    unsigned long long a = f2bits(acc), p = f2bits(pq);
    asm("v_pk_fma_f32 %0, %1, %2, %0 op_sel:[0,0,0] op_sel_hi:[1,0,1]"
        : "+v"(a) : "s"(w), "v"(p));
    acc = bits2f(a);
}
// acc.{lo,hi} += w.{lo,hi} * pq.hi   (Q broadcast: src1 hi word for both halves)
__device__ __forceinline__ void pkfma_Q(f2& acc, unsigned long long w, f2 pq) {
    unsigned long long a = f2bits(acc), p = f2bits(pq);
    asm("v_pk_fma_f32 %0, %1, %2, %0 op_sel:[0,1,0] op_sel_hi:[1,1,1]"
        : "+v"(a) : "s"(w), "v"(p));
    acc = bits2f(a);
}
// acc.{lo,hi} = w.{lo,hi} * pq.lo
__device__ __forceinline__ void pkmul_P(f2& acc, unsigned long long w, f2 pq) {
    unsigned long long a, p = f2bits(pq);
    asm("v_pk_mul_f32 %0, %1, %2 op_sel:[0,0] op_sel_hi:[1,0]"
        : "=v"(a) : "s"(w), "v"(p));
    acc = bits2f(a);
}

// ---------------------------------------------------------------- erosion + prep
// W layout (floats), all tables PAIR-indexed (o = oc>>1, half = oc&1):
//   [ (o*9+k)*2 + half ]          wp  (P-weight pair for taps k = ky*3+kx)
//   [ 288 + (o*9+k)*2 + half ]    wq  (Q-weight pair)
//   [ 576 + case*32 + o*2+half ]  D   (bias incl. b1; case 0=y0,1=interior,2=y511)
//   [ 672 + case*32 + o*2+half ]  EL  (x=0 column correction)
//   [ 768 + case*32 + o*2+half ]  ER  (x=511 column correction)
//   [ 864 + o*2 + half ]          w2  (output 1x1 weights)
struct Row8 { float4 a, b; };

__device__ __forceinline__ Row8 row_update8(const Row8 up, const Row8 mid, const Row8 dn)
{
    float v0 = vmin3(up.a.x, mid.a.x, dn.a.x);
    float v1 = vmin3(up.a.y, mid.a.y, dn.a.y);
    float v2 = vmin3(up.a.z, mid.a.z, dn.a.z);
    float v3 = vmin3(up.a.w, mid.a.w, dn.a.w);
    float v4 = vmin3(up.b.x, mid.b.x, dn.b.x);
    float v5 = vmin3(up.b.y, mid.b.y, dn.b.y);
    float v6 = vmin3(up.b.z, mid.b.z, dn.b.z);
    float v7 = vmin3(up.b.w, mid.b.w, dn.b.w);
    float vmL = dpp_shr1(v7, INF);   // left neighbor vmin; lane0 -> +inf image edge
    float vmR = dpp_shl1(v0, INF);   // right neighbor vmin; lane63 -> +inf image edge
    Row8 o;
    o.a.x = mid.a.x + vmin3(vmL, v0, v1);
    o.a.y = mid.a.y + vmin3(v0, v1, v2);
    o.a.z = mid.a.z + vmin3(v1, v2, v3);
    o.a.w = mid.a.w + vmin3(v2, v3, v4);
    o.b.x = mid.b.x + vmin3(v3, v4, v5);
    o.b.y = mid.b.y + vmin3(v4, v5, v6);
    o.b.z = mid.b.z + vmin3(v5, v6, v7);
    o.b.w = mid.b.w + vmin3(v6, v7, vmR);
    return o;
}

// per-lane contiguous 32B halo slot, XOR-16B swizzle for 2-way (free) banking.
__device__ __forceinline__ void halo_write(float* hp, int f0, int f1, const Row8& v) {
    *(float4*)(hp + f0) = v.a;
    *(float4*)(hp + f1) = v.b;
}
__device__ __forceinline__ Row8 halo_read(const float* hp, int f0, int f1) {
    Row8 v;
    v.a = *(const float4*)(hp + f0);
    v.b = *(const float4*)(hp + f1);
    return v;
}

// ---------------------------------------------------------------- head row
// Wave = one image row (64 lanes x 8 px). f2 packs OC-PAIRS (2o,2o+1); P/Q input
// scalars broadcast via op_sel pk_fma. Weights/bias via uniform s_loads; edge
// columns via masked packed FMAs; neighbor px via DPP (fill=0 = zero pad).
__device__ __forceinline__ void head_row(
    const float* __restrict__ A, const float* __restrict__ W,
    float bb, float* __restrict__ out, int img, int y, int lane)
{
    const int x0 = lane*8;
    const float* P = A + img*N_PIX;
    const float* Q = A + (8 + img)*N_PIX;

    f2 pq[3][10];
    #pragma unroll
    for (int dy = 0; dy < 3; ++dy) {
        int gy = y + dy - 1;
        if ((unsigned)gy < 512u) {               // wave-uniform branch
            const float* rp = P + gy*512 + x0;
            const float* rq = Q + gy*512 + x0;
            float4 a = *(const float4*)rp;
            float4 b = *(const float4*)(rp + 4);
            float4 c = *(const float4*)rq;
            float4 d = *(const float4*)(rq + 4);
            pq[dy][1] = (f2){a.x, c.x}; pq[dy][2] = (f2){a.y, c.y};
            pq[dy][3] = (f2){a.z, c.z}; pq[dy][4] = (f2){a.w, c.w};
            pq[dy][5] = (f2){b.x, d.x}; pq[dy][6] = (f2){b.y, d.y};
            pq[dy][7] = (f2){b.z, d.z}; pq[dy][8] = (f2){b.w, d.w};
            pq[dy][0] = (f2){dpp_shr1(b.w, 0.f), dpp_shr1(d.w, 0.f)};  // x0-1 (lane0 -> pad 0)
            pq[dy][9] = (f2){dpp_shl1(a.x, 0.f), dpp_shl1(c.x, 0.f)};  // x0+8 (lane63 -> pad 0)
        } else {
            #pragma unroll
            for (int j = 0; j < 10; ++j) pq[dy][j] = (f2){0.f, 0.f};
        }
    }

    // row-case tables (wave-uniform): 0 = y0, 1 = interior, 2 = y511
    const int wcase = (y == 0) ? 0 : ((y == 511) ? 2 : 1);
    const unsigned long long* WPv = (const unsigned long long*)W;          // [o*9+t]
    const unsigned long long* WQv = (const unsigned long long*)(W + 288);
    const f2* Dpv  = (const f2*)(W + 576 + wcase*32);   // [o] bias pairs
    const f2* ELv  = (const f2*)(W + 672 + wcase*32);
    const f2* ERv  = (const f2*)(W + 768 + wcase*32);
    const f2* w2v  = (const f2*)(W + 864);
    const float mLs = (lane == 0)  ? -1.f : 0.f;   // subtract-mask for x=0 col
    const float mRs = (lane == 63) ? -1.f : 0.f;   // subtract-mask for x=511 col
    const f2 mLp = (f2){mLs, mLs};
    const f2 mRp = (f2){mRs, mRs};

    f2 opk[8];
    #pragma unroll
    for (int j = 0; j < 8; ++j) opk[j] = (f2){0.f, 0.f};

    #pragma unroll 2
    for (int o = 0; o < 16; ++o) {
        f2 acc[8];
        {   // tap 0 (P): mul
            unsigned long long wv = WPv[o*9];
            #pragma unroll
            for (int j = 0; j < 8; ++j) pkmul_P(acc[j], wv, pq[0][j]);
        }
        #pragma unroll
        for (int t = 1; t < 9; ++t) {            // taps 1..8 (P)
            const int ky = t / 3, kx = t - ky*3;
            unsigned long long wv = WPv[o*9 + t];
            #pragma unroll
            for (int j = 0; j < 8; ++j) pkfma_P(acc[j], wv, pq[ky][kx + j]);
        }
        #pragma unroll
        for (int t = 0; t < 9; ++t) {            // taps 0..8 (Q)
            const int ky = t / 3, kx = t - ky*3;
            unsigned long long wv = WQv[o*9 + t];
            #pragma unroll
            for (int j = 0; j < 8; ++j) pkfma_Q(acc[j], wv, pq[ky][kx + j]);
        }
        f2 bp = Dpv[o];
        #pragma unroll
        for (int j = 0; j < 8; ++j) acc[j] += bp;     // v_pk_add: bias once per px
        acc[0] += ELv[o] * mLp;                       // x=0 column correction
        acc[7] += ERv[o] * mRp;                       // x=511 column correction
        f2 sc = w2v[o];
        #pragma unroll
        for (int j = 0; j < 8; ++j) {
            acc[j].x = fmaxf(acc[j].x, 0.f);          // relu per half (per oc)
            acc[j].y = fmaxf(acc[j].y, 0.f);
            opk[j] += acc[j] * sc;                    // packed w2 accumulation
        }
    }

    float o0 = opk[0].x + opk[0].y + bb, o1 = opk[1].x + opk[1].y + bb;
    float o2 = opk[2].x + opk[2].y + bb, o3 = opk[3].x + opk[3].y + bb;
    float o4 = opk[4].x + opk[4].y + bb, o5 = opk[5].x + opk[5].y + bb;
    float o6 = opk[6].x + opk[6].y + bb, o7 = opk[7].x + opk[7].y + bb;
    float* op = out + img*N_PIX + y*512 + x0;
    *(float4*)(op)     = make_float4(o0, o1, o2, o3);
    *(float4*)(op + 4) = make_float4(o4, o5, o6, o7);
}

// ---------------------------------------------------------------- fused kernel
__global__ __launch_bounds__(512, 2) void sdf_fused_kernel(
    const float* __restrict__ x, float* __restrict__ A,
    const float* __restrict__ w0, const float* __restrict__ b0,
    const float* __restrict__ w1, const float* __restrict__ b1,
    const float* __restrict__ w2, const float* __restrict__ b2,
    float* __restrict__ W, float* __restrict__ out)
{
    // prep fold (one block; W consumed by the head phase after grid.sync)
    if (blockIdx.x == 0 && blockIdx.y == 0 && threadIdx.x < 288) {
        int tid = threadIdx.x;
        int oc = tid / 9, k = tid - oc*9;
        int o = oc >> 1, hf = oc & 1;
        float wp = 0.f, wq = 0.f;
        for (int ic = 0; ic < 8; ++ic) {
            float a = w0[ic];
            float w = w1[oc*72 + ic*9 + k];
            if (a > 0.f) wp += w * a;
            else         wq += w * (-a);
        }
        W[(o*9 + k)*2 + hf]       = wp;
        W[288 + (o*9 + k)*2 + hf] = wq;
        if (k == 0) {
            float beta[9];
            for (int kk = 0; kk < 9; ++kk) {
                float s = 0.f;
                for (int ic = 0; ic < 8; ++ic) s += b0[ic] * w1[oc*72 + ic*9 + kk];
                beta[kk] = 65536.0f * s;   // bias doubles each of 16 iters
            }
            float R[3], Lb[3], Rr[3];
            for (int r = 0; r < 3; ++r) {
                R[r]  = beta[r*3] + beta[r*3+1] + beta[r*3+2];
                Lb[r] = beta[r*3 + 0];
                Rr[r] = beta[r*3 + 2];
            }
            float bb = b1[oc];
            // case 0: y=0 (ky=0 row out of image) ; case 1: interior ; case 2: y=511
            float Dv[3]  = { bb + R[1] + R[2], bb + R[0] + R[1] + R[2], bb + R[0] + R[1] };
            float ELv[3] = { Lb[1] + Lb[2], Lb[0] + Lb[1] + Lb[2], Lb[0] + Lb[1] };
            float ERv[3] = { Rr[1] + Rr[2], Rr[0] + Rr[1] + Rr[2], Rr[0] + Rr[1] };
            for (int c = 0; c < 3; ++c) {
                W[576 + c*32 + o*2 + hf] = Dv[c];   // full bias: added once per px
                W[672 + c*32 + o*2 + hf] = ELv[c];
                W[768 + c*32 + o*2 + hf] = ERv[c];
            }
            W[864 + o*2 + hf] = w2[oc];
        }
    }

    __shared__ float halo[2][8][4][512];     // [par][band][{r0,r1,r6,r7}][swizzled 512f] = 128 KB
    const int tid   = threadIdx.x;
    const int lane  = tid & 63;
    const int w     = tid >> 6;              // band 0..7, 8 rows each
    const int ty    = blockIdx.x;            // 0..15
    const int plane = blockIdx.y;            // 0..7 P(img), 8..15 Q(img)
    const int colg  = lane * 8;
    const int row0g = ty*32 - 16 + w*8;      // global row of h[0]

    // swizzled per-lane float offsets: lane*8 floats, XOR 16B-bit with lane bit2
    const int f0 = (lane*8)     ^ (lane & 4);
    const int f1 = (lane*8 + 4) ^ (lane & 4);

    // scalar copy of the band index, for the cone-skip branch only
    const int wS = __builtin_amdgcn_readfirstlane(w);
    const bool edge_band = (wS == 0) || (wS == 7);

    const float* sp = x + (plane & 7)*N_PIX;
    const float sgn = (plane >= 8) ? -1.f : 1.f;

    Row8 h[8];
    #pragma unroll
    for (int r = 0; r < 8; ++r) {
        int gy = row0g + r;
        if ((unsigned)gy < 512u) {
            const float* rp = sp + gy*512 + colg;
            float4 a = *(const float4*)rp;
            float4 b = *(const float4*)(rp + 4);
            h[r].a = make_float4(a.x*sgn, a.y*sgn, a.z*sgn, a.w*sgn);
            h[r].b = make_float4(b.x*sgn, b.y*sgn, b.z*sgn, b.w*sgn);
        } else {
            h[r].a = make_float4(INF, INF, INF, INF);
            h[r].b = h[r].a;
        }
    }

    const Row8 inf8 = { make_float4(INF,INF,INF,INF), make_float4(INF,INF,INF,INF) };
    for (int s = 0; s < 8; ++s) {            // 8 pairs = 16 steps
        int par = s & 1;
        // cone skip: bands 0/7's rows can't reach the valid 32 rows once s>=4.
        if (edge_band && s >= 4) { __syncthreads(); continue; }
        halo_write(&halo[par][w][0][0], f0, f1, h[0]);
        halo_write(&halo[par][w][1][0], f0, f1, h[1]);
        halo_write(&halo[par][w][2][0], f0, f1, h[6]);
        halo_write(&halo[par][w][3][0], f0, f1, h[7]);
        // step-A interior (no halo dependency) before the barrier
        Row8 n2 = row_update8(h[1], h[2], h[3]);
        Row8 n3 = row_update8(h[2], h[3], h[4]);
        Row8 n4 = row_update8(h[3], h[4], h[5]);
        Row8 n5 = row_update8(h[4], h[5], h[6]);
        __syncthreads();
        Row8 um2 = inf8, um1 = inf8, dp0 = inf8, dp1 = inf8;
        if (w > 0) {                         // prev band's old rows 6,7 = my rows -2,-1
            um2 = halo_read(&halo[par][w-1][2][0], f0, f1);
            um1 = halo_read(&halo[par][w-1][3][0], f0, f1);
        }
        if (w < 7) {                         // next band's old rows 0,1 = my rows 8,9
            dp0 = halo_read(&halo[par][w+1][0][0], f0, f1);
            dp1 = halo_read(&halo[par][w+1][1][0], f0, f1);
        }
        // step-A boundary rows
        Row8 nm1 = row_update8(um2, um1, h[0]);
        Row8 n0  = row_update8(um1, h[0], h[1]);
        Row8 n1  = row_update8(h[0], h[1], h[2]);
        Row8 n6  = row_update8(h[5], h[6], h[7]);
        Row8 n7  = row_update8(h[6], h[7], dp0);
        Row8 n8  = row_update8(h[7], dp0, dp1);
        // step B: rows 0..7 from n[-1..8]
        h[0] = row_update8(nm1, n0, n1);
        h[1] = row_update8(n0,  n1, n2);
        h[2] = row_update8(n1,  n2, n3);
        h[3] = row_update8(n2,  n3, n4);
        h[4] = row_update8(n3,  n4, n5);
        h[5] = row_update8(n4,  n5, n6);
        h[6] = row_update8(n5,  n6, n7);
        h[7] = row_update8(n6,  n7, n8);
    }

    // valid: bands 2..5 = staged rows [16,48) = global [ty*32, ty*32+32)
    if (w >= 2 && w <= 5) {
        float* dp = A + plane*N_PIX;
        #pragma unroll
        for (int r = 0; r < 8; ++r) {
            float* op = dp + (row0g + r)*512 + colg;
            *(float4*)op       = h[r].a;
            *(float4*)(op + 4) = h[r].b;
        }
    }

    // ---- grid-wide handoff: A and W written -> visible to all XCDs ----
    __threadfence();                         // device-scope release
    cg::this_grid().sync();                  // all 256 blocks co-resident (1/CU)

    // ---- head phase: block (ty,plane) does 16 rows of img = plane&7.
    // P-blocks (plane<8) take rows [ty*32, ty*32+16) -- their own P writes are
    // same-XCD L2 hits; Q-blocks take [ty*32+16, ty*32+32).
    const int img   = plane & 7;
    const int ybase = ty*32 + ((plane >= 8) ? 16 : 0);
    const float bb  = b2[0];
    #pragma unroll
    for (int k = 0; k < 2; ++k) {
        int y = ybase + w*2 + k;             // wave-uniform row
        head_row(A, W, bb, out, img, y, lane);
    }
}

// ---------------------------------------------------------------- launch
extern "C" void kernel_launch(void* const* d_in, const int* in_sizes, int n_in,
                              void* d_out, int out_size, void* d_ws, size_t ws_size,
                              hipStream_t stream) {
    const float* x  = (const float*)d_in[0];
    const float* w0 = (const float*)d_in[1];
    const float* b0 = (const float*)d_in[2];
    const float* w1 = (const float*)d_in[3];
    const float* b1 = (const float*)d_in[4];
    const float* w2 = (const float*)d_in[5];
    const float* b2 = (const float*)d_in[6];
    float* out = (float*)d_out;

    float* wsf = (float*)d_ws;
    float* A = wsf;                 // 16 planes (P imgs 0..7, Q imgs 8..15), 16.8 MB
    float* W = wsf + 16*N_PIX;      // 896 floats of folded weights/bias tables

    void* args[] = { (void*)&x, (void*)&A, (void*)&w0, (void*)&b0, (void*)&w1,
                     (void*)&b1, (void*)&w2, (void*)&b2, (void*)&W, (void*)&out };
    hipLaunchCooperativeKernel((const void*)sdf_fused_kernel,
                               dim3(16, 16), dim3(512), args, 0, stream);
}

// Round 5
// 120.454 us; speedup vs baseline: 2.0664x; 2.0664x over previous
//
#include <hip/hip_runtime.h>
#include <math.h>

// SDFNet: conv1x1(1->8) -> 16x (h += minpool3(h)) -> conv3x3(8->32) -> relu -> conv1x1(32->1)
//
// Factorization: erosion steps act per-channel on affine maps of x.
//   w0[c] > 0: h_c after 16 iters = w0[c]*P16(x) + b0[c]*2^16   (P = min-iterate of x)
//   w0[c] < 0: h_c = |w0[c]|*Q16 + b0[c]*2^16, Q = min-iterate of -x (pad +inf exact)
// Head = 3x3 conv over (P,Q) with folded weights, bias beta = 65536*sum_ic b0*w1
// applied only for in-image taps (ref zero-pads h).
//
// R8:  cross-lane +/-1 shifts via wave-wide DPP (old = INF/0 fill).
// R9:  2 erosion steps per barrier; prep folded into erode.
// R13: row_update8 via v_min3_f32 (26 VALU); bands 0/7 whole-body cone skip s>=4.
// R14: b128 halo exchange (XOR-16B swizzle); head packs oc-pairs in f2 with P/Q
//      broadcast via VOP3P op_sel pk_fma.
// R15: cooperative-kernel fusion. [REVERTED: grid.sync() = serialized device-scope
//      atomics across 8 non-coherent L2s, ~0.5us/block x 256 = +140us. Refuted.]
// R16: revert to R14 two-dispatch form + head block->row remap so head block on
//      XCD k reads A tile-rows written by erode blocks on XCD k:
//      erode (ty,plane) -> XCD (ty+16*plane)%8 = ty%8 (all 16 planes of a tile-row
//      on one XCD, 2MB < 4MB L2). head b: xcd=b&7, ty in {xcd, xcd+8} -> ~94% of
//      A-reads are same-XCD L2 hits (only +-1 tile-boundary rows cross).

#define N_PIX (512*512)
#define INF __builtin_inff()

typedef __attribute__((ext_vector_type(2))) float f2;

__device__ __forceinline__ unsigned long long f2bits(f2 v) {
    union { f2 f; unsigned long long u; } c; c.f = v; return c.u;
}
__device__ __forceinline__ f2 bits2f(unsigned long long u) {
    union { f2 f; unsigned long long u; } c; c.u = u; return c.f;
}

// lane l gets v[l-1]; lane 0 gets `fill`   (DPP wave_shr1 = 0x138, VALU pipe)
__device__ __forceinline__ float dpp_shr1(float v, float fill) {
    return __int_as_float(__builtin_amdgcn_update_dpp(
        __float_as_int(fill), __float_as_int(v), 0x138, 0xF, 0xF, false));
}
// lane l gets v[l+1]; lane 63 gets `fill`  (DPP wave_shl1 = 0x130)
__device__ __forceinline__ float dpp_shl1(float v, float fill) {
    return __int_as_float(__builtin_amdgcn_update_dpp(
        __float_as_int(fill), __float_as_int(v), 0x130, 0xF, 0xF, false));
}
// single-instruction 3-input min (IEEE minnum semantics, exact for finite/+inf)
__device__ __forceinline__ float vmin3(float a, float b, float c) {
    float d;
    asm("v_min3_f32 %0, %1, %2, %3" : "=v"(d) : "v"(a), "v"(b), "v"(c));
    return d;
}

// ---- packed fma with scalar broadcast via op_sel --------------------------
// acc.{lo,hi} += w.{lo,hi} * pq.lo   (P broadcast: src1 lo word for both halves)
__device__ __forceinline__ void pkfma_P(f2& acc, unsigned long long w, f2 pq) {
    unsigned long long a = f2bits(acc), p = f2bits(pq);
    asm("v_pk_fma_f32 %0, %1, %2, %0 op_sel:[0,0,0] op_sel_hi:[1,0,1]"
        : "+v"(a) : "s"(w), "v"(p));
    acc = bits2f(a);
}
// acc.{lo,hi} += w.{lo,hi} * pq.hi   (Q broadcast: src1 hi word for both halves)
__device__ __forceinline__ void pkfma_Q(f2& acc, unsigned long long w, f2 pq) {
    unsigned long long a = f2bits(acc), p = f2bits(pq);
    asm("v_pk_fma_f32 %0, %1, %2, %0 op_sel:[0,1,0] op_sel_hi:[1,1,1]"
        : "+v"(a) : "s"(w), "v"(p));
    acc = bits2f(a);
}
// acc.{lo,hi} = w.{lo,hi} * pq.lo
__device__ __forceinline__ void pkmul_P(f2& acc, unsigned long long w, f2 pq) {
    unsigned long long a, p = f2bits(pq);
    asm("v_pk_mul_f32 %0, %1, %2 op_sel:[0,0] op_sel_hi:[1,0]"
        : "=v"(a) : "s"(w), "v"(p));
    acc = bits2f(a);
}

// ---------------------------------------------------------------- erosion + prep
// W layout (floats), all tables PAIR-indexed (o = oc>>1, half = oc&1):
//   [ (o*9+k)*2 + half ]          wp  (P-weight pair for taps k = ky*3+kx)
//   [ 288 + (o*9+k)*2 + half ]    wq  (Q-weight pair)
//   [ 576 + case*32 + o*2+half ]  D   (bias incl. b1; case 0=y0,1=interior,2=y511)
//   [ 672 + case*32 + o*2+half ]  EL  (x=0 column correction)
//   [ 768 + case*32 + o*2+half ]  ER  (x=511 column correction)
//   [ 864 + o*2 + half ]          w2  (output 1x1 weights)
struct Row8 { float4 a, b; };

__device__ __forceinline__ Row8 row_update8(const Row8 up, const Row8 mid, const Row8 dn)
{
    float v0 = vmin3(up.a.x, mid.a.x, dn.a.x);
    float v1 = vmin3(up.a.y, mid.a.y, dn.a.y);
    float v2 = vmin3(up.a.z, mid.a.z, dn.a.z);
    float v3 = vmin3(up.a.w, mid.a.w, dn.a.w);
    float v4 = vmin3(up.b.x, mid.b.x, dn.b.x);
    float v5 = vmin3(up.b.y, mid.b.y, dn.b.y);
    float v6 = vmin3(up.b.z, mid.b.z, dn.b.z);
    float v7 = vmin3(up.b.w, mid.b.w, dn.b.w);
    float vmL = dpp_shr1(v7, INF);   // left neighbor vmin; lane0 -> +inf image edge
    float vmR = dpp_shl1(v0, INF);   // right neighbor vmin; lane63 -> +inf image edge
    Row8 o;
    o.a.x = mid.a.x + vmin3(vmL, v0, v1);
    o.a.y = mid.a.y + vmin3(v0, v1, v2);
    o.a.z = mid.a.z + vmin3(v1, v2, v3);
    o.a.w = mid.a.w + vmin3(v2, v3, v4);
    o.b.x = mid.b.x + vmin3(v3, v4, v5);
    o.b.y = mid.b.y + vmin3(v4, v5, v6);
    o.b.z = mid.b.z + vmin3(v5, v6, v7);
    o.b.w = mid.b.w + vmin3(v6, v7, vmR);
    return o;
}

// per-lane contiguous 32B halo slot, XOR-16B swizzle for 2-way (free) banking.
// f0/f1 precomputed per lane; exchange is across bands at the SAME lane, so any
// per-lane layout permutation is correctness-neutral.
__device__ __forceinline__ void halo_write(float* hp, int f0, int f1, const Row8& v) {
    *(float4*)(hp + f0) = v.a;
    *(float4*)(hp + f1) = v.b;
}
__device__ __forceinline__ Row8 halo_read(const float* hp, int f0, int f1) {
    Row8 v;
    v.a = *(const float4*)(hp + f0);
    v.b = *(const float4*)(hp + f1);
    return v;
}

__global__ __launch_bounds__(512, 2) void erode16_kernel(
    const float* __restrict__ x, float* __restrict__ A,
    const float* __restrict__ w0, const float* __restrict__ b0,
    const float* __restrict__ w1, const float* __restrict__ b1,
    const float* __restrict__ w2, float* __restrict__ W)
{
    // prep fold (one block; W consumed only by the later head dispatch)
    if (blockIdx.x == 0 && blockIdx.y == 0 && threadIdx.x < 288) {
        int tid = threadIdx.x;
        int oc = tid / 9, k = tid - oc*9;
        int o = oc >> 1, hf = oc & 1;
        float wp = 0.f, wq = 0.f;
        for (int ic = 0; ic < 8; ++ic) {
            float a = w0[ic];
            float w = w1[oc*72 + ic*9 + k];
            if (a > 0.f) wp += w * a;
            else         wq += w * (-a);
        }
        W[(o*9 + k)*2 + hf]       = wp;
        W[288 + (o*9 + k)*2 + hf] = wq;
        if (k == 0) {
            float beta[9];
            for (int kk = 0; kk < 9; ++kk) {
                float s = 0.f;
                for (int ic = 0; ic < 8; ++ic) s += b0[ic] * w1[oc*72 + ic*9 + kk];
                beta[kk] = 65536.0f * s;   // bias doubles each of 16 iters
            }
            float R[3], Lb[3], Rr[3];
            for (int r = 0; r < 3; ++r) {
                R[r]  = beta[r*3] + beta[r*3+1] + beta[r*3+2];
                Lb[r] = beta[r*3 + 0];
                Rr[r] = beta[r*3 + 2];
            }
            float bb = b1[oc];
            // case 0: y=0 (ky=0 row out of image) ; case 1: interior ; case 2: y=511
            float Dv[3]  = { bb + R[1] + R[2], bb + R[0] + R[1] + R[2], bb + R[0] + R[1] };
            float ELv[3] = { Lb[1] + Lb[2], Lb[0] + Lb[1] + Lb[2], Lb[0] + Lb[1] };
            float ERv[3] = { Rr[1] + Rr[2], Rr[0] + Rr[1] + Rr[2], Rr[0] + Rr[1] };
            for (int c = 0; c < 3; ++c) {
                W[576 + c*32 + o*2 + hf] = Dv[c];   // full bias: added once per px
                W[672 + c*32 + o*2 + hf] = ELv[c];
                W[768 + c*32 + o*2 + hf] = ERv[c];
            }
            W[864 + o*2 + hf] = w2[oc];
        }
    }

    __shared__ float halo[2][8][4][512];     // [par][band][{r0,r1,r6,r7}][swizzled 512f] = 128 KB
    const int tid   = threadIdx.x;
    const int lane  = tid & 63;
    const int w     = tid >> 6;              // band 0..7, 8 rows each
    const int ty    = blockIdx.x;            // 0..15
    const int plane = blockIdx.y;            // 0..7 P(img), 8..15 Q(img)
    const int colg  = lane * 8;
    const int row0g = ty*32 - 16 + w*8;      // global row of h[0]

    // swizzled per-lane float offsets: lane*8 floats, XOR 16B-bit with lane bit2
    const int f0 = (lane*8)     ^ (lane & 4);
    const int f1 = (lane*8 + 4) ^ (lane & 4);

    // scalar copy of the band index, for the cone-skip branch only
    const int wS = __builtin_amdgcn_readfirstlane(w);
    const bool edge_band = (wS == 0) || (wS == 7);

    const float* sp = x + (plane & 7)*N_PIX;
    const float sgn = (plane >= 8) ? -1.f : 1.f;

    Row8 h[8];
    #pragma unroll
    for (int r = 0; r < 8; ++r) {
        int gy = row0g + r;
        if ((unsigned)gy < 512u) {
            const float* rp = sp + gy*512 + colg;
            float4 a = *(const float4*)rp;
            float4 b = *(const float4*)(rp + 4);
            h[r].a = make_float4(a.x*sgn, a.y*sgn, a.z*sgn, a.w*sgn);
            h[r].b = make_float4(b.x*sgn, b.y*sgn, b.z*sgn, b.w*sgn);
        } else {
            h[r].a = make_float4(INF, INF, INF, INF);
            h[r].b = h[r].a;
        }
    }

    const Row8 inf8 = { make_float4(INF,INF,INF,INF), make_float4(INF,INF,INF,INF) };
    for (int s = 0; s < 8; ++s) {            // 8 pairs = 16 steps
        int par = s & 1;
        // cone skip: bands 0/7's rows can't reach the valid 32 rows once s>=4.
        if (edge_band && s >= 4) { __syncthreads(); continue; }
        halo_write(&halo[par][w][0][0], f0, f1, h[0]);
        halo_write(&halo[par][w][1][0], f0, f1, h[1]);
        halo_write(&halo[par][w][2][0], f0, f1, h[6]);
        halo_write(&halo[par][w][3][0], f0, f1, h[7]);
        // step-A interior (no halo dependency) before the barrier
        Row8 n2 = row_update8(h[1], h[2], h[3]);
        Row8 n3 = row_update8(h[2], h[3], h[4]);
        Row8 n4 = row_update8(h[3], h[4], h[5]);
        Row8 n5 = row_update8(h[4], h[5], h[6]);
        __syncthreads();
        Row8 um2 = inf8, um1 = inf8, dp0 = inf8, dp1 = inf8;
        if (w > 0) {                         // prev band's old rows 6,7 = my rows -2,-1
            um2 = halo_read(&halo[par][w-1][2][0], f0, f1);
            um1 = halo_read(&halo[par][w-1][3][0], f0, f1);
        }
        if (w < 7) {                         // next band's old rows 0,1 = my rows 8,9
            dp0 = halo_read(&halo[par][w+1][0][0], f0, f1);
            dp1 = halo_read(&halo[par][w+1][1][0], f0, f1);
        }
        // step-A boundary rows
        Row8 nm1 = row_update8(um2, um1, h[0]);
        Row8 n0  = row_update8(um1, h[0], h[1]);
        Row8 n1  = row_update8(h[0], h[1], h[2]);
        Row8 n6  = row_update8(h[5], h[6], h[7]);
        Row8 n7  = row_update8(h[6], h[7], dp0);
        Row8 n8  = row_update8(h[7], dp0, dp1);
        // step B: rows 0..7 from n[-1..8]
        h[0] = row_update8(nm1, n0, n1);
        h[1] = row_update8(n0,  n1, n2);
        h[2] = row_update8(n1,  n2, n3);
        h[3] = row_update8(n2,  n3, n4);
        h[4] = row_update8(n3,  n4, n5);
        h[5] = row_update8(n4,  n5, n6);
        h[6] = row_update8(n5,  n6, n7);
        h[7] = row_update8(n6,  n7, n8);
    }

    // valid: bands 2..5 = staged rows [16,48) = global [ty*32, ty*32+32)
    if (w >= 2 && w <= 5) {
        float* dp = A + plane*N_PIX;
        #pragma unroll
        for (int r = 0; r < 8; ++r) {
            float* op = dp + (row0g + r)*512 + colg;
            *(float4*)op       = h[r].a;
            *(float4*)(op + 4) = h[r].b;
        }
    }
}

// ---------------------------------------------------------------- head
// Wave = one image row (64 lanes x 8 px). f2 packs OC-PAIRS (2o,2o+1); P/Q input
// scalars broadcast into both halves via op_sel pk_fma. Weights/bias via uniform
// s_loads; row-case picked per wave; edge columns via masked packed FMAs; neighbor
// px via DPP (fill=0 = zero pad).
// R16 block remap: xcd=b&7 picks which tile-rows this block handles (ty=xcd or
// xcd+8), so A-reads hit the same XCD's L2 that erode dirtied (ty%8 == xcd).
__global__ __launch_bounds__(256) void head_kernel(
    const float* __restrict__ A, const float* __restrict__ W,
    const float* __restrict__ b2, float* __restrict__ out)
{
    const int tid  = threadIdx.x;
    const int lane = tid & 63;
    const int w    = tid >> 6;
    const int b    = blockIdx.x;                 // 0..1023
    const int xcd  = b & 7;                      // this block's XCD (b % 8)
    const int j    = b >> 3;                     // 0..127
    const int img  = j >> 4;                     // 0..7
    const int t    = j & 15;                     // 16 blocks per (img, xcd)
    const int ty   = xcd + ((t & 1) << 3);       // tile-row: ty % 8 == xcd
    const int y    = ty*32 + ((t >> 1) << 2) + w;// wave-uniform row
    const int x0   = lane*8;

    const float* P = A + img*N_PIX;
    const float* Q = A + (8 + img)*N_PIX;

    f2 pq[3][10];
    #pragma unroll
    for (int dy = 0; dy < 3; ++dy) {
        int gy = y + dy - 1;
        if ((unsigned)gy < 512u) {               // wave-uniform branch
            const float* rp = P + gy*512 + x0;
            const float* rq = Q + gy*512 + x0;
            float4 a = *(const float4*)rp;
            float4 b4 = *(const float4*)(rp + 4);
            float4 c = *(const float4*)rq;
            float4 d = *(const float4*)(rq + 4);
            pq[dy][1] = (f2){a.x, c.x}; pq[dy][2] = (f2){a.y, c.y};
            pq[dy][3] = (f2){a.z, c.z}; pq[dy][4] = (f2){a.w, c.w};
            pq[dy][5] = (f2){b4.x, d.x}; pq[dy][6] = (f2){b4.y, d.y};
            pq[dy][7] = (f2){b4.z, d.z}; pq[dy][8] = (f2){b4.w, d.w};
            pq[dy][0] = (f2){dpp_shr1(b4.w, 0.f), dpp_shr1(d.w, 0.f)};  // x0-1 (lane0 -> pad 0)
            pq[dy][9] = (f2){dpp_shl1(a.x, 0.f), dpp_shl1(c.x, 0.f)};   // x0+8 (lane63 -> pad 0)
        } else {
            #pragma unroll
            for (int jj = 0; jj < 10; ++jj) pq[dy][jj] = (f2){0.f, 0.f};
        }
    }

    // row-case tables (wave-uniform): 0 = y0, 1 = interior, 2 = y511
    const int wcase = (y == 0) ? 0 : ((y == 511) ? 2 : 1);
    const unsigned long long* WPv = (const unsigned long long*)W;          // [o*9+t]
    const unsigned long long* WQv = (const unsigned long long*)(W + 288);
    const f2* Dpv  = (const f2*)(W + 576 + wcase*32);   // [o] bias pairs
    const f2* ELv  = (const f2*)(W + 672 + wcase*32);
    const f2* ERv  = (const f2*)(W + 768 + wcase*32);
    const f2* w2v  = (const f2*)(W + 864);
    const float mLs = (lane == 0)  ? -1.f : 0.f;   // subtract-mask for x=0 col
    const float mRs = (lane == 63) ? -1.f : 0.f;   // subtract-mask for x=511 col
    const f2 mLp = (f2){mLs, mLs};
    const f2 mRp = (f2){mRs, mRs};

    f2 opk[8];
    #pragma unroll
    for (int jj = 0; jj < 8; ++jj) opk[jj] = (f2){0.f, 0.f};

    #pragma unroll 2
    for (int o = 0; o < 16; ++o) {
        f2 acc[8];
        {   // tap 0 (P): mul
            unsigned long long wv = WPv[o*9];
            #pragma unroll
            for (int jj = 0; jj < 8; ++jj) pkmul_P(acc[jj], wv, pq[0][jj]);
        }
        #pragma unroll
        for (int tt = 1; tt < 9; ++tt) {         // taps 1..8 (P)
            const int ky = tt / 3, kx = tt - ky*3;
            unsigned long long wv = WPv[o*9 + tt];
            #pragma unroll
            for (int jj = 0; jj < 8; ++jj) pkfma_P(acc[jj], wv, pq[ky][kx + jj]);
        }
        #pragma unroll
        for (int tt = 0; tt < 9; ++tt) {         // taps 0..8 (Q)
            const int ky = tt / 3, kx = tt - ky*3;
            unsigned long long wv = WQv[o*9 + tt];
            #pragma unroll
            for (int jj = 0; jj < 8; ++jj) pkfma_Q(acc[jj], wv, pq[ky][kx + jj]);
        }
        f2 bp = Dpv[o];
        #pragma unroll
        for (int jj = 0; jj < 8; ++jj) acc[jj] += bp;  // v_pk_add: bias once per px
        acc[0] += ELv[o] * mLp;                        // x=0 column correction
        acc[7] += ERv[o] * mRp;                        // x=511 column correction
        f2 sc = w2v[o];
        #pragma unroll
        for (int jj = 0; jj < 8; ++jj) {
            acc[jj].x = fmaxf(acc[jj].x, 0.f);         // relu per half (per oc)
            acc[jj].y = fmaxf(acc[jj].y, 0.f);
            opk[jj] += acc[jj] * sc;                   // packed w2 accumulation
        }
    }

    float bb = b2[0];
    float o0 = opk[0].x + opk[0].y + bb, o1 = opk[1].x + opk[1].y + bb;
    float o2 = opk[2].x + opk[2].y + bb, o3 = opk[3].x + opk[3].y + bb;
    float o4 = opk[4].x + opk[4].y + bb, o5 = opk[5].x + opk[5].y + bb;
    float o6 = opk[6].x + opk[6].y + bb, o7 = opk[7].x + opk[7].y + bb;
    float* op = out + img*N_PIX + y*512 + x0;
    *(float4*)(op)     = make_float4(o0, o1, o2, o3);
    *(float4*)(op + 4) = make_float4(o4, o5, o6, o7);
}

// ---------------------------------------------------------------- launch
extern "C" void kernel_launch(void* const* d_in, const int* in_sizes, int n_in,
                              void* d_out, int out_size, void* d_ws, size_t ws_size,
                              hipStream_t stream) {
    const float* x  = (const float*)d_in[0];
    const float* w0 = (const float*)d_in[1];
    const float* b0 = (const float*)d_in[2];
    const float* w1 = (const float*)d_in[3];
    const float* b1 = (const float*)d_in[4];
    const float* w2 = (const float*)d_in[5];
    const float* b2 = (const float*)d_in[6];
    float* out = (float*)d_out;

    float* wsf = (float*)d_ws;
    float* A = wsf;                 // 16 planes (P imgs 0..7, Q imgs 8..15), 16.8 MB
    float* W = wsf + 16*N_PIX;      // 896 floats of folded weights/bias tables

    dim3 eg(16, 16);
    erode16_kernel<<<eg, 512, 0, stream>>>(x, A, w0, b0, w1, b1, w2, W);  // 16 steps + prep

    head_kernel<<<1024, 256, 0, stream>>>(A, W, b2, out);
}